// Round 6
// baseline (1575.412 us; speedup 1.0000x reference)
//
#include <hip/hip_runtime.h>
#include <math.h>

#define PI_F 3.14159265358979323846f

// ---------------- workspace layout (float offsets) ----------------
#define OFF_SF     0           // 32768
#define OFF_EMB    32768       // 65536
#define OFF_M      98304       // 32768
#define OFF_CK     131072      // 131072  (2,H,N) cpx
#define OFF_KC     262144      // 524288  (H,2048)
#define OFF_C1     786432      // 98304
#define OFF_C2     884736      // 49152
#define OFF_WT     933888      // 1572864
#define OFF_W32    2506752     // 2097152
#define OFF_W1     4603904     // 2097152
#define OFF_XMOD   6701056     // 8388608
#define OFF_H      15089664    // 8388608
#define OFF_Z      23478272    // 8388608
#define OFF_FLAG   31866880    // 16 (int flag)
#define OFF_ADAW   31866896    // 2097152
#define OFF_TRANSW 33964048    // 65536
#define OFF_OUTW   34029584    // 65536
#define OFF_PROJW  34095120    // 131072
#define OFF_LINW   34226192    // 524288
#define OFF_TR1W   34750480    // 2304
#define OFF_ADAB   34752784    // 2048
#define OFF_TRANSB 34754832    // 256
#define OFF_NORMG  34755088    // 256
#define OFF_NORMB  34755344    // 256
#define OFF_LOGDT  34755600    // 256
#define OFF_AR     34755856    // 32768
#define OFF_AI     34788624    // 32768
#define OFF_CRE    34821392    // 65536
#define OFF_CIM    34886928    // 65536
#define OFF_DP     34952464    // 256
#define OFF_OUTB   34952720    // 256
#define OFF_PROJB  34952976    // 512
#define OFF_TR1B   34953488    // 4
#define OFF_TR2B   34953492    // 512
#define OFF_LINB   34954004    // 512
// end ~34954516 floats = 133.3 MB

// ---------------- output layout (f32 element offsets) ----------------
#define OOUT0   0
#define OOUT1   8388608
#define OTREND  8404992
#define OSEASON 12599296

// ================= helpers =================
__device__ __forceinline__ float bf2f(unsigned short u) {
  union { unsigned u; float f; } c; c.u = ((unsigned)u) << 16;
  return c.f;
}

// ================= K0a: input dtype detector (kept for robustness) =================
__global__ void k_detect(const void* xin, int* flag) {
  __shared__ int cnt[64];
  int tid = threadIdx.x;   // 64 threads, 1 block
  const unsigned short* u = (const unsigned short*)xin;
  int c = 0;
  for (int k = 0; k < 64; ++k) {
    unsigned short v = u[tid * 64 + k];
    int e = (v >> 7) & 0xFF;
    if ((v & 0x7FFF) == 0 || (e >= 96 && e <= 159)) ++c;
  }
  cnt[tid] = c;
  __syncthreads();
  if (tid == 0) {
    int s = 0;
    for (int k = 0; k < 64; ++k) s += cnt[k];
    *flag = (s >= 3482) ? 1 : 0;   // 85% of 4096
  }
}

// ================= K0b: flag-driven input -> f32 =================
__global__ void k_cvt(const void* in, float* outp, int n, const int* flag) {
  int i = blockIdx.x * 256 + threadIdx.x;
  if (i >= n) return;
  if (*flag) outp[i] = bf2f(((const unsigned short*)in)[i]);
  else       outp[i] = ((const float*)in)[i];
}

// ================= K1a: silu(time-embedding features) =================
__global__ void k_sf(const int* __restrict__ t, float* __restrict__ sf) {
  int gid = blockIdx.x * 256 + threadIdx.x;   // 32768
  int b = gid >> 10, i = gid & 1023;
  float tf = (float)t[b];
  const float cc = -logf(10000.0f) / 511.0f;
  float v;
  if (i < 512) v = sinf(tf * expf(cc * (float)i));
  else         v = cosf(tf * expf(cc * (float)(i - 512)));
  sf[gid] = v / (1.0f + expf(-v));   // silu
}

// ================= K1b: emb = silu_feats @ ada_W^T + ada_b =================
__global__ void k_emb(const float* __restrict__ sf, const float* __restrict__ aW,
                      const float* __restrict__ ab, float* __restrict__ emb) {
  __shared__ float red[64];
  int o = blockIdx.x, b = blockIdx.y, lane = threadIdx.x;  // block 64
  const float* s = sf + b * 1024;
  const float* w = aW + o * 1024;
  float acc = 0.0f;
  #pragma unroll
  for (int k = 0; k < 16; ++k) { int i = lane + 64 * k; acc += s[i] * w[i]; }
  red[lane] = acc;
  __syncthreads();
  for (int st = 32; st; st >>= 1) {
    if (lane < st) red[lane] += red[lane + st];
    __syncthreads();
  }
  if (lane == 0) emb[b * 2048 + o] = red[0] + ab[o];
}

// ================= K2: LN over L (no affine) + modulate =================
__global__ __launch_bounds__(256) void k_ln_mod(const void* __restrict__ xin,
                                                const float* __restrict__ emb,
                                                float* __restrict__ xmod,
                                                const int* __restrict__ flag) {
  __shared__ float red[256];
  int tid = threadIdx.x;
  int row = blockIdx.x;               // b*256+h
  int b = row >> 8;
  size_t base = (size_t)row * 1024 + tid * 4;
  float4 v;
  if (*flag) {
    ushort4 u = *(const ushort4*)&((const unsigned short*)xin)[base];
    v = make_float4(bf2f(u.x), bf2f(u.y), bf2f(u.z), bf2f(u.w));
  } else {
    v = *(const float4*)&((const float*)xin)[base];
  }
  red[tid] = v.x + v.y + v.z + v.w;
  __syncthreads();
  for (int st = 128; st; st >>= 1) {
    if (tid < st) red[tid] += red[tid + st];
    __syncthreads();
  }
  float mean = red[0] * (1.0f / 1024.0f);
  __syncthreads();
  float dx = v.x - mean, dy = v.y - mean, dz = v.z - mean, dw = v.w - mean;
  red[tid] = dx * dx + dy * dy + dz * dz + dw * dw;
  __syncthreads();
  for (int st = 128; st; st >>= 1) {
    if (tid < st) red[tid] += red[tid + st];
    __syncthreads();
  }
  float var = red[0] * (1.0f / 1024.0f);
  float inv = 1.0f / sqrtf(var + 1e-5f);
  const float4 sc = *(const float4*)&emb[b * 2048 + tid * 4];
  const float4 sh = *(const float4*)&emb[b * 2048 + 1024 + tid * 4];
  float4 r;
  r.x = dx * inv * (1.0f + sc.x) + sh.x;
  r.y = dy * inv * (1.0f + sc.y) + sh.y;
  r.z = dz * inv * (1.0f + sc.z) + sh.z;
  r.w = dw * inv * (1.0f + sc.w) + sh.w;
  *(float4*)&xmod[base] = r;
}

// ================= K2b: m = mean over H =================
__global__ __launch_bounds__(256) void k_meanH(const float* __restrict__ xm, float* __restrict__ m) {
  __shared__ float p[4][64];
  int tid = threadIdx.x, lq = tid & 63, part = tid >> 6;
  int b = blockIdx.x >> 4, l = (blockIdx.x & 15) * 64 + lq;
  const float* xp = xm + (size_t)b * 262144 + l;
  float s = 0.0f;
  for (int k = 0; k < 64; ++k) s += xp[(part * 64 + k) * 1024];
  p[part][lq] = s;
  __syncthreads();
  if (part == 0) m[b * 1024 + l] = (p[0][lq] + p[1][lq] + p[2][lq] + p[3][lq]) * (1.0f / 256.0f);
}

// ================= K2c: out0 = xmod - m  (f32 out) =================
__global__ void k_sub(const float* __restrict__ xm, const float* __restrict__ m,
                      float* __restrict__ o0) {
  size_t flat = ((size_t)blockIdx.x * 256 + threadIdx.x) * 4;
  int l = (int)(flat & 1023); int b = (int)(flat >> 18);
  float4 v = *(const float4*)&xm[flat];
  const float4 mv = *(const float4*)&m[b * 1024 + l];
  v.x -= mv.x; v.y -= mv.y; v.z -= mv.z; v.w -= mv.w;
  *(float4*)&o0[flat] = v;
}

// ================= K2d: out1 = m @ lin_W^T + lin_b  (f32 out) =================
__global__ void k_lin(const float* __restrict__ m, const float* __restrict__ lw,
                      const float* __restrict__ lb, float* __restrict__ o1) {
  __shared__ float red[64];
  int node = blockIdx.x, b = blockIdx.y, lane = threadIdx.x;  // block 64
  const float* mp = m + b * 1024;
  const float* wp = lw + node * 1024;
  float acc = 0.0f;
  #pragma unroll
  for (int k = 0; k < 16; ++k) { int l = lane + 64 * k; acc += mp[l] * wp[l]; }
  red[lane] = acc;
  __syncthreads();
  for (int st = 32; st; st >>= 1) {
    if (lane < st) red[lane] += red[lane + st];
    __syncthreads();
  }
  if (lane == 0) o1[b * 512 + node] = red[0] + lb[node];
}

// ================= channel matmul =================
// MODE 0: + extra (X may be bf16 per flag)   MODE 1: + extra, swish   MODE 2: bias only
template<int MODE>
__global__ __launch_bounds__(256) void k_mm(const float* __restrict__ W, const void* __restrict__ Xin,
                                            const float* __restrict__ bias, const float* __restrict__ extra,
                                            float* __restrict__ out, int o_base,
                                            const int* __restrict__ flag) {
  __shared__ __align__(16) float Xs[8][64];
  __shared__ __align__(16) float Ws[8][64];
  int tid = threadIdx.x;
  int b = blockIdx.z;
  int l0 = blockIdx.x * 64, o0 = blockIdx.y * 64;
  int tx = tid & 15, ty = tid >> 4;
  float acc[4][4] = {};
  bool xbf = false;
  if (MODE == 0) xbf = (*flag != 0);
  const float* Xf = (const float*)Xin;
  const unsigned short* Xu = (const unsigned short*)Xin;
  size_t xbase = (size_t)b * 262144;
  int li = tid & 63, lj = tid >> 6;
  int wi = tid >> 2, wj = (tid & 3) * 2;
  for (int k0 = 0; k0 < 256; k0 += 8) {
    size_t i1 = xbase + (size_t)(k0 + lj) * 1024 + l0 + li;
    size_t i2 = i1 + 4 * 1024;
    if (MODE == 0 && xbf) {
      Xs[lj][li]     = bf2f(Xu[i1]);
      Xs[lj + 4][li] = bf2f(Xu[i2]);
    } else {
      Xs[lj][li]     = Xf[i1];
      Xs[lj + 4][li] = Xf[i2];
    }
    float w0 = W[(o_base + o0 + wi) * 256 + k0 + wj];
    float w1 = W[(o_base + o0 + wi) * 256 + k0 + wj + 1];
    Ws[wj][wi] = w0; Ws[wj + 1][wi] = w1;
    __syncthreads();
    #pragma unroll
    for (int j2 = 0; j2 < 8; ++j2) {
      const float4 xv = *(const float4*)&Xs[j2][tx * 4];
      const float4 wv = *(const float4*)&Ws[j2][ty * 4];
      acc[0][0] += wv.x * xv.x; acc[0][1] += wv.x * xv.y; acc[0][2] += wv.x * xv.z; acc[0][3] += wv.x * xv.w;
      acc[1][0] += wv.y * xv.x; acc[1][1] += wv.y * xv.y; acc[1][2] += wv.y * xv.z; acc[1][3] += wv.y * xv.w;
      acc[2][0] += wv.z * xv.x; acc[2][1] += wv.z * xv.y; acc[2][2] += wv.z * xv.z; acc[2][3] += wv.z * xv.w;
      acc[3][0] += wv.w * xv.x; acc[3][1] += wv.w * xv.y; acc[3][2] += wv.w * xv.z; acc[3][3] += wv.w * xv.w;
    }
    __syncthreads();
  }
  #pragma unroll
  for (int r = 0; r < 4; ++r) {
    int o = o0 + ty * 4 + r;
    float bv = bias[o_base + o];
    size_t oidx = ((size_t)b * 256 + o) * 1024 + l0 + tx * 4;
    float4 res;
    res.x = acc[r][0] + bv; res.y = acc[r][1] + bv; res.z = acc[r][2] + bv; res.w = acc[r][3] + bv;
    if (MODE == 0) {
      const float4 e = *(const float4*)&extra[oidx];
      res.x += e.x; res.y += e.y; res.z += e.z; res.w += e.w;
    } else if (MODE == 1) {
      const float4 e = *(const float4*)&extra[oidx];
      float v0 = res.x + e.x, v1 = res.y + e.y, v2 = res.z + e.z, v3 = res.w + e.w;
      res.x = tanhf(v0) * (1.0f / (1.0f + expf(-v0)));
      res.y = tanhf(v1) * (1.0f / (1.0f + expf(-v1)));
      res.z = tanhf(v2) * (1.0f / (1.0f + expf(-v2)));
      res.w = tanhf(v3) * (1.0f / (1.0f + expf(-v3)));
    }
    *(float4*)&out[oidx] = res;
  }
}

// ================= K4: LN over H with affine =================
__global__ __launch_bounds__(256) void k_lnH(const float* __restrict__ hbuf, const float* __restrict__ g,
                                             const float* __restrict__ bn, float* __restrict__ z) {
  __shared__ float p1[4][64], p2[4][64];
  int tid = threadIdx.x, lq = tid & 63, part = tid >> 6;
  int b = blockIdx.x >> 4, l = (blockIdx.x & 15) * 64 + lq;
  const float* hp = hbuf + (size_t)b * 262144 + l;
  float s1 = 0.0f, s2 = 0.0f;
  for (int k = 0; k < 64; ++k) {
    float v = hp[(part * 64 + k) * 1024];
    s1 += v; s2 += v * v;
  }
  p1[part][lq] = s1; p2[part][lq] = s2;
  __syncthreads();
  if (part == 0) {
    float a1 = (p1[0][lq] + p1[1][lq] + p1[2][lq] + p1[3][lq]) * (1.0f / 256.0f);
    float a2 = (p2[0][lq] + p2[1][lq] + p2[2][lq] + p2[3][lq]) * (1.0f / 256.0f);
    float var = a2 - a1 * a1;
    p1[0][lq] = a1;
    p2[0][lq] = 1.0f / sqrtf(var + 1e-5f);
  }
  __syncthreads();
  float mean = p1[0][lq], inv = p2[0][lq];
  float* zp = z + (size_t)b * 262144 + l;
  for (int k = 0; k < 64; ++k) {
    int hh = part * 64 + k;
    float v = hp[hh * 1024];
    zp[hh * 1024] = (v - mean) * inv * g[hh] + bn[hh];
  }
}

// ================= K5: dt/A twiddle tables + Ck =================
__global__ void k_tab(const float* __restrict__ log_dt, const float* __restrict__ Ar,
                      const float* __restrict__ Ai, const float* __restrict__ Cre,
                      const float* __restrict__ Cim,
                      float2* __restrict__ W32, float2* __restrict__ W1, float2* __restrict__ Ck) {
  int gid = blockIdx.x * 256 + threadIdx.x;   // 32768 = H*N
  int h = gid >> 7;
  float dt = expf(log_dt[h]);
  float ar = -expf(Ar[gid]);
  float ai = Ai[gid];
  float dre = dt * ar, dim = dt * ai;
  size_t tb = (size_t)gid * 32;
  for (int j = 0; j < 32; ++j) {
    float sn, cs;
    float e = expf(dre * (float)j);
    sincosf(dim * (float)j, &sn, &cs);
    W1[tb + j] = make_float2(e * cs, e * sn);
    float aj = 32.0f * (float)j;
    float e2 = expf(dre * aj);
    sincosf(dim * aj, &sn, &cs);
    W32[tb + j] = make_float2(e2 * cs, e2 * sn);
  }
  float sn, cs;
  float er = expf(dre);
  sincosf(dim, &sn, &cs);
  float exr = er * cs - 1.0f, exi = er * sn;   // exp(dtA)-1
  float den = ar * ar + ai * ai;               // |A|^2
  float qr = (exr * ar + exi * ai) / den;      // (exp(dtA)-1)/A
  float qi = (exi * ar - exr * ai) / den;
  #pragma unroll
  for (int c = 0; c < 2; ++c) {
    float cr = Cre[c * 32768 + gid], ci = Cim[c * 32768 + gid];
    Ck[c * 32768 + gid] = make_float2(cr * qr - ci * qi, cr * qi + ci * qr);
  }
}

// ================= K6: combined conv kernel Kc =================
__global__ void k_kc(const float2* __restrict__ W32, const float2* __restrict__ W1,
                     const float2* __restrict__ Ck, float* __restrict__ Kc) {
  int j2 = blockIdx.x * 256 + threadIdx.x;  // 0..2047
  int h = blockIdx.y;
  int c, l;
  if (j2 >= 1024) { c = 0; l = j2 - 1024; } else { c = 1; l = 1023 - j2; }
  int l1 = l >> 5, l0 = l & 31;
  const float2* wa = W32 + (size_t)h * 4096;
  const float2* wb = W1 + (size_t)h * 4096;
  const float2* ck = Ck + c * 32768 + h * 128;
  float acc = 0.0f;
  for (int n = 0; n < 128; ++n) {
    float2 a = wa[n * 32 + l1];
    float2 bq = wb[n * 32 + l0];
    float2 k = ck[n];
    float wr = a.x * bq.x - a.y * bq.y;
    float wi = a.x * bq.y + a.y * bq.x;
    acc += k.x * wr - k.y * wi;
  }
  Kc[h * 2048 + j2] = 2.0f * acc;
}

// ================= K7: direct conv + Dp*z + gelu (in place over z) =================
__global__ __launch_bounds__(128) void k_conv(float* __restrict__ z, const float* __restrict__ Kc,
                                              const float* __restrict__ Dp) {
  __shared__ __align__(16) float zs[1024];
  __shared__ __align__(16) float ks[2048];
  int tid = threadIdx.x;
  size_t row = (size_t)blockIdx.x * 1024;
  int h = blockIdx.x & 255;
  #pragma unroll
  for (int q = 0; q < 2; ++q)
    *(float4*)&zs[tid * 8 + q * 4] = *(const float4*)&z[row + tid * 8 + q * 4];
  #pragma unroll
  for (int q = 0; q < 4; ++q)
    *(float4*)&ks[tid * 16 + q * 4] = *(const float4*)&Kc[h * 2048 + tid * 16 + q * 4];
  __syncthreads();
  int l0 = tid * 8;
  float acc[8] = {};
  for (int mc = 0; mc < 256; ++mc) {
    int m0 = mc * 4;
    const float4 zv = *(const float4*)&zs[m0];
    int base = l0 - m0 + 1020;
    const float4 w0 = *(const float4*)&ks[base];
    const float4 w1 = *(const float4*)&ks[base + 4];
    const float4 w2 = *(const float4*)&ks[base + 8];
    float wf[12] = {w0.x, w0.y, w0.z, w0.w, w1.x, w1.y, w1.z, w1.w, w2.x, w2.y, w2.z, w2.w};
    float zr[4] = {zv.x, zv.y, zv.z, zv.w};
    #pragma unroll
    for (int r = 0; r < 4; ++r) {
      #pragma unroll
      for (int s = 0; s < 8; ++s) acc[s] += zr[r] * wf[s + 4 - r];
    }
  }
  float dp = Dp[h];
  #pragma unroll
  for (int s = 0; s < 8; ++s) {
    float u = acc[s] + dp * zs[l0 + s];
    acc[s] = 0.5f * u * (1.0f + tanhf(0.7978845608028654f * (u + 0.044715f * u * u * u)));
  }
  *(float4*)&z[row + l0]     = make_float4(acc[0], acc[1], acc[2], acc[3]);
  *(float4*)&z[row + l0 + 4] = make_float4(acc[4], acc[5], acc[6], acc[7]);
}

// ================= K10: c1 = relu(conv3_channels(out1)) =================
__global__ __launch_bounds__(128) void k_c1(const float* __restrict__ x1, const float* __restrict__ w,
                                            const float* __restrict__ bb, float* __restrict__ c1) {
  __shared__ float wl[2304];
  int tid = threadIdx.x;
  int b = blockIdx.y, l = blockIdx.x * 128 + tid;
  for (int i = tid; i < 2304; i += 128) wl[i] = w[i];
  __syncthreads();
  const float* xp = x1 + (size_t)b * 262144;
  float a0 = 0.0f, a1 = 0.0f, a2 = 0.0f;
  for (int i = 0; i < 256; ++i) {
    const float* r = xp + i * 1024;
    float v0 = (l >= 1)    ? r[l - 1] : 0.0f;
    float v1 = r[l];
    float v2 = (l <= 1022) ? r[l + 1] : 0.0f;
    const float* w0 = &wl[i * 3];
    a0 += v0 * w0[0]    + v1 * w0[1]    + v2 * w0[2];
    a1 += v0 * w0[768]  + v1 * w0[769]  + v2 * w0[770];
    a2 += v0 * w0[1536] + v1 * w0[1537] + v2 * w0[1538];
  }
  c1[((size_t)b * 3 + 0) * 1024 + l] = fmaxf(a0 + bb[0], 0.0f);
  c1[((size_t)b * 3 + 1) * 1024 + l] = fmaxf(a1 + bb[1], 0.0f);
  c1[((size_t)b * 3 + 2) * 1024 + l] = fmaxf(a2 + bb[2], 0.0f);
}

// ================= K11a: transpose+convert tr2_W (o,i,k)->(i,k,o) =================
__global__ void k_wt(const void* __restrict__ w, float* __restrict__ wt,
                     const int* __restrict__ flag) {
  int gid = blockIdx.x * 256 + threadIdx.x;   // 1572864
  int o = gid & 511, ik = gid >> 9;
  float v;
  if (*flag) v = bf2f(((const unsigned short*)w)[o * 3072 + ik]);
  else       v = ((const float*)w)[o * 3072 + ik];
  wt[gid] = v;
}

// ================= K11: c2 = conv3 over swapped axes =================
__global__ __launch_bounds__(128) void k_c2(const float* __restrict__ c1, const float* __restrict__ wt,
                                            const float* __restrict__ bb, float* __restrict__ c2) {
  __shared__ float c1s[3072];
  int tid = threadIdx.x;
  int b = blockIdx.y, o = blockIdx.x * 128 + tid;
  for (int i = tid; i < 3072; i += 128) c1s[i] = c1[(size_t)b * 3072 + i];
  __syncthreads();
  float a0 = 0.0f, a1 = 0.0f, a2 = 0.0f;
  for (int i = 0; i < 1024; ++i) {
    float w0 = wt[(i * 3 + 0) * 512 + o];
    float w1 = wt[(i * 3 + 1) * 512 + o];
    float w2 = wt[(i * 3 + 2) * 512 + o];
    float x0 = c1s[i], x1 = c1s[1024 + i], x2 = c1s[2048 + i];
    a0 += w1 * x0 + w2 * x1;
    a1 += w0 * x0 + w1 * x1 + w2 * x2;
    a2 += w0 * x1 + w1 * x2;
  }
  float bv = bb[o];
  c2[((size_t)b * 512 + o) * 3 + 0] = a0 + bv;
  c2[((size_t)b * 512 + o) * 3 + 1] = a1 + bv;
  c2[((size_t)b * 512 + o) * 3 + 2] = a2 + bv;
}

// ================= K12: trend = swap(c2 @ poly)  (f32 out) =================
__global__ void k_trend(const float* __restrict__ c2, float* __restrict__ tr) {
  int gid = blockIdx.x * 256 + threadIdx.x;   // 4194304
  int node = gid & 511, h = (gid >> 9) & 255, b = gid >> 17;
  float lin = (float)(h + 1) * (1.0f / 257.0f);
  const float* cp = &c2[((size_t)b * 512 + node) * 3];
  float l2 = lin * lin;
  tr[gid] = cp[0] * lin + cp[1] * l2 + cp[2] * l2 * lin;
}

// ================= K13: FFT over channel axis, top-4, season (f32 out) =================
__global__ __launch_bounds__(256) void k_fft(const float* __restrict__ xin,
                                             float* __restrict__ season) {
  __shared__ float2 S[256][17];
  __shared__ float2 W[128];
  __shared__ float ampL[4][16], frL[4][16], phL[4][16];
  int tid = threadIdx.x;
  int b = blockIdx.y, d0 = blockIdx.x * 16;
  const float* xp = xin + (size_t)b * 262144 + d0;
  if (tid < 128) {
    float sn, cs;
    sincosf((2.0f * PI_F / 256.0f) * (float)tid, &sn, &cs);
    W[tid] = make_float2(cs, -sn);
  }
  #pragma unroll
  for (int r = 0; r < 16; ++r) {
    int idx = tid + 256 * r;
    int t = idx >> 4, c = idx & 15;
    int rt = (int)(__brev((unsigned)t) >> 24);
    S[rt][c] = make_float2(xp[t * 1024 + c], 0.0f);
  }
  __syncthreads();
  for (int s = 0; s < 8; ++s) {
    int half = 1 << s;
    #pragma unroll
    for (int r = 0; r < 8; ++r) {
      int item = tid + 256 * r;
      int c = item & 15, p = item >> 4;
      int j = p & (half - 1);
      int i1 = ((p >> s) << (s + 1)) | j;
      int i2 = i1 + half;
      float2 tw = W[j << (7 - s)];
      float2 a = S[i1][c], bb = S[i2][c];
      float2 tv = make_float2(tw.x * bb.x - tw.y * bb.y, tw.x * bb.y + tw.y * bb.x);
      S[i1][c] = make_float2(a.x + tv.x, a.y + tv.y);
      S[i2][c] = make_float2(a.x - tv.x, a.y - tv.y);
    }
    __syncthreads();
  }
  if (tid < 16) {
    int c = tid;
    float bm0 = -1.0f, bm1 = -1.0f, bm2 = -1.0f, bm3 = -1.0f;
    int k0 = 1, k1 = 1, k2 = 1, k3 = 1;
    for (int k = 1; k <= 127; ++k) {
      float2 v = S[k][c];
      float m2 = v.x * v.x + v.y * v.y;
      if (m2 > bm0)      { bm3 = bm2; k3 = k2; bm2 = bm1; k2 = k1; bm1 = bm0; k1 = k0; bm0 = m2; k0 = k; }
      else if (m2 > bm1) { bm3 = bm2; k3 = k2; bm2 = bm1; k2 = k1; bm1 = m2; k1 = k; }
      else if (m2 > bm2) { bm3 = bm2; k3 = k2; bm2 = m2; k2 = k; }
      else if (m2 > bm3) { bm3 = m2; k3 = k; }
    }
    int ks4[4] = {k0, k1, k2, k3};
    #pragma unroll
    for (int s = 0; s < 4; ++s) {
      int k = ks4[s];
      float2 v = S[k][c];
      ampL[s][c] = 2.0f * sqrtf(v.x * v.x + v.y * v.y);
      phL[s][c] = atan2f(v.y, v.x);
      frL[s][c] = (2.0f * PI_F / 256.0f) * (float)k;
    }
  }
  __syncthreads();
  #pragma unroll
  for (int r = 0; r < 16; ++r) {
    int idx = tid + 256 * r;
    int t = idx >> 4, c = idx & 15;
    float acc = 0.0f;
    #pragma unroll
    for (int s = 0; s < 4; ++s) acc += ampL[s][c] * cosf(frL[s][c] * (float)t + phL[s][c]);
    season[(size_t)b * 262144 + t * 1024 + d0 + c] = acc;
  }
}

// ================= launch =================
extern "C" void kernel_launch(void* const* d_in, const int* in_sizes, int n_in,
                              void* d_out, int out_size, void* d_ws, size_t ws_size,
                              hipStream_t stream) {
  const void* x       = d_in[0];
  const int*  t       = (const int*)d_in[1];
  const void* x_enc   = d_in[2];
  (void)in_sizes; (void)n_in; (void)out_size; (void)ws_size;

  float* out = (float*)d_out;    // f32 outputs (reference output dtype)
  float* ws  = (float*)d_ws;
  float* sf   = ws + OFF_SF;
  float* emb  = ws + OFF_EMB;
  float* m    = ws + OFF_M;
  float2* Ck  = (float2*)(ws + OFF_CK);
  float* Kc   = ws + OFF_KC;
  float* c1   = ws + OFF_C1;
  float* c2   = ws + OFF_C2;
  float* wt   = ws + OFF_WT;
  float2* W32 = (float2*)(ws + OFF_W32);
  float2* W1  = (float2*)(ws + OFF_W1);
  float* xmod = ws + OFF_XMOD;
  float* hbuf = ws + OFF_H;
  float* zbuf = ws + OFF_Z;
  int*   flagp = (int*)(ws + OFF_FLAG);

  // 0. detect input dtype (bf16 vs f32), then convert weights/vectors to f32
  k_detect<<<1, 64, 0, stream>>>(x, flagp);
  #define CVT(idx, off, n) k_cvt<<<((n) + 255) / 256, 256, 0, stream>>>(d_in[idx], ws + (off), (n), flagp)
  CVT(3,  OFF_ADAW,   2097152);   // ada_W
  CVT(4,  OFF_ADAB,   2048);      // ada_b
  CVT(5,  OFF_TRANSW, 65536);     // trans_W
  CVT(6,  OFF_TRANSB, 256);       // trans_b
  CVT(7,  OFF_NORMG,  256);       // norm_g
  CVT(8,  OFF_NORMB,  256);       // norm_b
  CVT(9,  OFF_LOGDT,  256);       // log_dt
  CVT(10, OFF_AR,     32768);     // A_real
  CVT(11, OFF_AI,     32768);     // A_imag
  CVT(12, OFF_CRE,    65536);     // C_re
  CVT(13, OFF_CIM,    65536);     // C_im
  CVT(14, OFF_DP,     256);       // Dp
  CVT(15, OFF_OUTW,   65536);     // out_W
  CVT(16, OFF_OUTB,   256);       // out_b
  CVT(17, OFF_PROJW,  131072);    // proj_W
  CVT(18, OFF_PROJB,  512);       // proj_b
  CVT(19, OFF_TR1W,   2304);      // tr1_W
  CVT(20, OFF_TR1B,   3);         // tr1_b
  CVT(22, OFF_TR2B,   512);       // tr2_b
  CVT(23, OFF_LINW,   524288);    // lin_W
  CVT(24, OFF_LINB,   512);       // lin_b
  #undef CVT

  // 1. time embedding -> modulation params
  k_sf<<<128, 256, 0, stream>>>(t, sf);
  k_emb<<<dim3(2048, 32), 64, 0, stream>>>(sf, ws + OFF_ADAW, ws + OFF_ADAB, emb);
  // 2. LN(L) + modulate
  k_ln_mod<<<8192, 256, 0, stream>>>(x, emb, xmod, flagp);
  // outputs 0/1 early
  k_meanH<<<512, 256, 0, stream>>>(xmod, m);
  k_sub<<<8192, 256, 0, stream>>>(xmod, m, out + OOUT0);
  k_lin<<<dim3(512, 32), 64, 0, stream>>>(m, ws + OFF_LINW, ws + OFF_LINB, out + OOUT1);
  // 3. h = xmod + trans_W @ x_enc + trans_b
  k_mm<0><<<dim3(16, 4, 32), 256, 0, stream>>>(ws + OFF_TRANSW, x_enc, ws + OFF_TRANSB, xmod, hbuf, 0, flagp);
  // 4. z = LN_H(h) * g + b
  k_lnH<<<512, 256, 0, stream>>>(hbuf, ws + OFF_NORMG, ws + OFF_NORMB, zbuf);
  // 5. S4 kernel
  k_tab<<<128, 256, 0, stream>>>(ws + OFF_LOGDT, ws + OFF_AR, ws + OFF_AI, ws + OFF_CRE, ws + OFF_CIM, W32, W1, Ck);
  k_kc<<<dim3(8, 256), 256, 0, stream>>>(W32, W1, Ck, Kc);
  // 6. y = conv(z,Kc); gelu(y + Dp*z) in place
  k_conv<<<8192, 128, 0, stream>>>(zbuf, Kc, ws + OFF_DP);
  // 7. out = swish(out_W @ ygelu + out_b + h)
  k_mm<1><<<dim3(16, 4, 32), 256, 0, stream>>>(ws + OFF_OUTW, zbuf, ws + OFF_OUTB, hbuf, xmod, 0, flagp);
  // 8. p = proj_W @ out + proj_b; halves -> zbuf (out1) / hbuf (out2)
  k_mm<2><<<dim3(16, 4, 32), 256, 0, stream>>>(ws + OFF_PROJW, xmod, ws + OFF_PROJB, ws, zbuf, 0, flagp);
  k_mm<2><<<dim3(16, 4, 32), 256, 0, stream>>>(ws + OFF_PROJW, xmod, ws + OFF_PROJB, ws, hbuf, 256, flagp);
  // 9. trend path
  k_c1<<<dim3(8, 32), 128, 0, stream>>>(zbuf, ws + OFF_TR1W, ws + OFF_TR1B, c1);
  k_wt<<<6144, 256, 0, stream>>>(d_in[21], wt, flagp);
  k_c2<<<dim3(4, 32), 128, 0, stream>>>(c1, wt, ws + OFF_TR2B, c2);
  k_trend<<<16384, 256, 0, stream>>>(c2, out + OTREND);
  // 10. season path
  k_fft<<<dim3(64, 32), 256, 0, stream>>>(hbuf, out + OSEASON);
}

// Round 10
// 1298.509 us; speedup vs baseline: 1.2132x; 1.2132x over previous
//
#include <hip/hip_runtime.h>
#include <math.h>

#define PI_F 3.14159265358979323846f

// ---------------- workspace layout (float offsets) ----------------
#define OFF_SF     0           // 32768
#define OFF_EMB    32768       // 65536
#define OFF_M      98304       // 32768
#define OFF_CK     131072      // 131072  (2,H,N) cpx
#define OFF_KC     262144      // 524288  (H,2048)
#define OFF_C1     786432      // 98304
#define OFF_C2     884736      // 49152
#define OFF_WT     933888      // 1572864
#define OFF_W32    2506752     // 2097152
#define OFF_W1     4603904     // 2097152
#define OFF_XMOD   6701056     // 8388608
#define OFF_H      15089664    // 8388608
#define OFF_Z      23478272    // 8388608
#define OFF_FLAG   31866880    // 16 (int flag)
#define OFF_ADAW   31866896    // 2097152
#define OFF_TRANSW 33964048    // 65536
#define OFF_OUTW   34029584    // 65536
#define OFF_PROJW  34095120    // 131072
#define OFF_LINW   34226192    // 524288
#define OFF_TR1W   34750480    // 2304
#define OFF_ADAB   34752784    // 2048
#define OFF_TRANSB 34754832    // 256
#define OFF_NORMG  34755088    // 256
#define OFF_NORMB  34755344    // 256
#define OFF_LOGDT  34755600    // 256
#define OFF_AR     34755856    // 32768
#define OFF_AI     34788624    // 32768
#define OFF_CRE    34821392    // 65536
#define OFF_CIM    34886928    // 65536
#define OFF_DP     34952464    // 256
#define OFF_OUTB   34952720    // 256
#define OFF_PROJB  34952976    // 512
#define OFF_TR1B   34953488    // 4
#define OFF_TR2B   34953492    // 512
#define OFF_LINB   34954004    // 512
// end ~34954516 floats = 133.3 MB

// ---------------- output layout (f32 element offsets) ----------------
#define OOUT0   0
#define OOUT1   8388608
#define OTREND  8404992
#define OSEASON 12599296

// ================= helpers =================
__device__ __forceinline__ float bf2f(unsigned short u) {
  union { unsigned u; float f; } c; c.u = ((unsigned)u) << 16;
  return c.f;
}

// ================= K0a: input dtype detector (kept for robustness) =================
__global__ void k_detect(const void* xin, int* flag) {
  __shared__ int cnt[64];
  int tid = threadIdx.x;   // 64 threads, 1 block
  const unsigned short* u = (const unsigned short*)xin;
  int c = 0;
  for (int k = 0; k < 64; ++k) {
    unsigned short v = u[tid * 64 + k];
    int e = (v >> 7) & 0xFF;
    if ((v & 0x7FFF) == 0 || (e >= 96 && e <= 159)) ++c;
  }
  cnt[tid] = c;
  __syncthreads();
  if (tid == 0) {
    int s = 0;
    for (int k = 0; k < 64; ++k) s += cnt[k];
    *flag = (s >= 3482) ? 1 : 0;   // 85% of 4096
  }
}

// ================= K0b: flag-driven input -> f32 =================
__global__ void k_cvt(const void* in, float* outp, int n, const int* flag) {
  int i = blockIdx.x * 256 + threadIdx.x;
  if (i >= n) return;
  if (*flag) outp[i] = bf2f(((const unsigned short*)in)[i]);
  else       outp[i] = ((const float*)in)[i];
}

// ================= K1a: silu(time-embedding features) =================
__global__ void k_sf(const int* __restrict__ t, float* __restrict__ sf) {
  int gid = blockIdx.x * 256 + threadIdx.x;   // 32768
  int b = gid >> 10, i = gid & 1023;
  float tf = (float)t[b];
  const float cc = -logf(10000.0f) / 511.0f;
  float v;
  if (i < 512) v = sinf(tf * expf(cc * (float)i));
  else         v = cosf(tf * expf(cc * (float)(i - 512)));
  sf[gid] = v / (1.0f + expf(-v));   // silu
}

// ================= K1b: emb = silu_feats @ ada_W^T + ada_b =================
__global__ void k_emb(const float* __restrict__ sf, const float* __restrict__ aW,
                      const float* __restrict__ ab, float* __restrict__ emb) {
  __shared__ float red[64];
  int o = blockIdx.x, b = blockIdx.y, lane = threadIdx.x;  // block 64
  const float* s = sf + b * 1024;
  const float* w = aW + o * 1024;
  float acc = 0.0f;
  #pragma unroll
  for (int k = 0; k < 16; ++k) { int i = lane + 64 * k; acc += s[i] * w[i]; }
  red[lane] = acc;
  __syncthreads();
  for (int st = 32; st; st >>= 1) {
    if (lane < st) red[lane] += red[lane + st];
    __syncthreads();
  }
  if (lane == 0) emb[b * 2048 + o] = red[0] + ab[o];
}

// ================= K2: LN over L (no affine) + modulate =================
__global__ __launch_bounds__(256) void k_ln_mod(const void* __restrict__ xin,
                                                const float* __restrict__ emb,
                                                float* __restrict__ xmod,
                                                const int* __restrict__ flag) {
  __shared__ float red[256];
  int tid = threadIdx.x;
  int row = blockIdx.x;               // b*256+h
  int b = row >> 8;
  size_t base = (size_t)row * 1024 + tid * 4;
  float4 v;
  if (*flag) {
    ushort4 u = *(const ushort4*)&((const unsigned short*)xin)[base];
    v = make_float4(bf2f(u.x), bf2f(u.y), bf2f(u.z), bf2f(u.w));
  } else {
    v = *(const float4*)&((const float*)xin)[base];
  }
  red[tid] = v.x + v.y + v.z + v.w;
  __syncthreads();
  for (int st = 128; st; st >>= 1) {
    if (tid < st) red[tid] += red[tid + st];
    __syncthreads();
  }
  float mean = red[0] * (1.0f / 1024.0f);
  __syncthreads();
  float dx = v.x - mean, dy = v.y - mean, dz = v.z - mean, dw = v.w - mean;
  red[tid] = dx * dx + dy * dy + dz * dz + dw * dw;
  __syncthreads();
  for (int st = 128; st; st >>= 1) {
    if (tid < st) red[tid] += red[tid + st];
    __syncthreads();
  }
  float var = red[0] * (1.0f / 1024.0f);
  float inv = 1.0f / sqrtf(var + 1e-5f);
  const float4 sc = *(const float4*)&emb[b * 2048 + tid * 4];
  const float4 sh = *(const float4*)&emb[b * 2048 + 1024 + tid * 4];
  float4 r;
  r.x = dx * inv * (1.0f + sc.x) + sh.x;
  r.y = dy * inv * (1.0f + sc.y) + sh.y;
  r.z = dz * inv * (1.0f + sc.z) + sh.z;
  r.w = dw * inv * (1.0f + sc.w) + sh.w;
  *(float4*)&xmod[base] = r;
}

// ================= K2b: m = mean over H =================
__global__ __launch_bounds__(256) void k_meanH(const float* __restrict__ xm, float* __restrict__ m) {
  __shared__ float p[4][64];
  int tid = threadIdx.x, lq = tid & 63, part = tid >> 6;
  int b = blockIdx.x >> 4, l = (blockIdx.x & 15) * 64 + lq;
  const float* xp = xm + (size_t)b * 262144 + l;
  float s = 0.0f;
  for (int k = 0; k < 64; ++k) s += xp[(part * 64 + k) * 1024];
  p[part][lq] = s;
  __syncthreads();
  if (part == 0) m[b * 1024 + l] = (p[0][lq] + p[1][lq] + p[2][lq] + p[3][lq]) * (1.0f / 256.0f);
}

// ================= K2c: out0 = xmod - m  (f32 out) =================
__global__ void k_sub(const float* __restrict__ xm, const float* __restrict__ m,
                      float* __restrict__ o0) {
  size_t flat = ((size_t)blockIdx.x * 256 + threadIdx.x) * 4;
  int l = (int)(flat & 1023); int b = (int)(flat >> 18);
  float4 v = *(const float4*)&xm[flat];
  const float4 mv = *(const float4*)&m[b * 1024 + l];
  v.x -= mv.x; v.y -= mv.y; v.z -= mv.z; v.w -= mv.w;
  *(float4*)&o0[flat] = v;
}

// ================= K2d: out1 = m @ lin_W^T + lin_b  (f32 out) =================
__global__ void k_lin(const float* __restrict__ m, const float* __restrict__ lw,
                      const float* __restrict__ lb, float* __restrict__ o1) {
  __shared__ float red[64];
  int node = blockIdx.x, b = blockIdx.y, lane = threadIdx.x;  // block 64
  const float* mp = m + b * 1024;
  const float* wp = lw + node * 1024;
  float acc = 0.0f;
  #pragma unroll
  for (int k = 0; k < 16; ++k) { int l = lane + 64 * k; acc += mp[l] * wp[l]; }
  red[lane] = acc;
  __syncthreads();
  for (int st = 32; st; st >>= 1) {
    if (lane < st) red[lane] += red[lane + st];
    __syncthreads();
  }
  if (lane == 0) o1[b * 512 + node] = red[0] + lb[node];
}

// ================= channel matmul =================
// MODE 0: + extra (X may be bf16 per flag)   MODE 1: + extra, swish   MODE 2: bias only
template<int MODE>
__global__ __launch_bounds__(256) void k_mm(const float* __restrict__ W, const void* __restrict__ Xin,
                                            const float* __restrict__ bias, const float* __restrict__ extra,
                                            float* __restrict__ out, int o_base,
                                            const int* __restrict__ flag) {
  __shared__ __align__(16) float Xs[8][64];
  __shared__ __align__(16) float Ws[8][64];
  int tid = threadIdx.x;
  int b = blockIdx.z;
  int l0 = blockIdx.x * 64, o0 = blockIdx.y * 64;
  int tx = tid & 15, ty = tid >> 4;
  float acc[4][4] = {};
  bool xbf = false;
  if (MODE == 0) xbf = (*flag != 0);
  const float* Xf = (const float*)Xin;
  const unsigned short* Xu = (const unsigned short*)Xin;
  size_t xbase = (size_t)b * 262144;
  int li = tid & 63, lj = tid >> 6;
  int wi = tid >> 2, wj = (tid & 3) * 2;
  for (int k0 = 0; k0 < 256; k0 += 8) {
    size_t i1 = xbase + (size_t)(k0 + lj) * 1024 + l0 + li;
    size_t i2 = i1 + 4 * 1024;
    if (MODE == 0 && xbf) {
      Xs[lj][li]     = bf2f(Xu[i1]);
      Xs[lj + 4][li] = bf2f(Xu[i2]);
    } else {
      Xs[lj][li]     = Xf[i1];
      Xs[lj + 4][li] = Xf[i2];
    }
    float w0 = W[(o_base + o0 + wi) * 256 + k0 + wj];
    float w1 = W[(o_base + o0 + wi) * 256 + k0 + wj + 1];
    Ws[wj][wi] = w0; Ws[wj + 1][wi] = w1;
    __syncthreads();
    #pragma unroll
    for (int j2 = 0; j2 < 8; ++j2) {
      const float4 xv = *(const float4*)&Xs[j2][tx * 4];
      const float4 wv = *(const float4*)&Ws[j2][ty * 4];
      acc[0][0] += wv.x * xv.x; acc[0][1] += wv.x * xv.y; acc[0][2] += wv.x * xv.z; acc[0][3] += wv.x * xv.w;
      acc[1][0] += wv.y * xv.x; acc[1][1] += wv.y * xv.y; acc[1][2] += wv.y * xv.z; acc[1][3] += wv.y * xv.w;
      acc[2][0] += wv.z * xv.x; acc[2][1] += wv.z * xv.y; acc[2][2] += wv.z * xv.z; acc[2][3] += wv.z * xv.w;
      acc[3][0] += wv.w * xv.x; acc[3][1] += wv.w * xv.y; acc[3][2] += wv.w * xv.z; acc[3][3] += wv.w * xv.w;
    }
    __syncthreads();
  }
  #pragma unroll
  for (int r = 0; r < 4; ++r) {
    int o = o0 + ty * 4 + r;
    float bv = bias[o_base + o];
    size_t oidx = ((size_t)b * 256 + o) * 1024 + l0 + tx * 4;
    float4 res;
    res.x = acc[r][0] + bv; res.y = acc[r][1] + bv; res.z = acc[r][2] + bv; res.w = acc[r][3] + bv;
    if (MODE == 0) {
      const float4 e = *(const float4*)&extra[oidx];
      res.x += e.x; res.y += e.y; res.z += e.z; res.w += e.w;
    } else if (MODE == 1) {
      const float4 e = *(const float4*)&extra[oidx];
      float v0 = res.x + e.x, v1 = res.y + e.y, v2 = res.z + e.z, v3 = res.w + e.w;
      res.x = tanhf(v0) * (1.0f / (1.0f + expf(-v0)));
      res.y = tanhf(v1) * (1.0f / (1.0f + expf(-v1)));
      res.z = tanhf(v2) * (1.0f / (1.0f + expf(-v2)));
      res.w = tanhf(v3) * (1.0f / (1.0f + expf(-v3)));
    }
    *(float4*)&out[oidx] = res;
  }
}

// ================= K4: LN over H with affine =================
__global__ __launch_bounds__(256) void k_lnH(const float* __restrict__ hbuf, const float* __restrict__ g,
                                             const float* __restrict__ bn, float* __restrict__ z) {
  __shared__ float p1[4][64], p2[4][64];
  int tid = threadIdx.x, lq = tid & 63, part = tid >> 6;
  int b = blockIdx.x >> 4, l = (blockIdx.x & 15) * 64 + lq;
  const float* hp = hbuf + (size_t)b * 262144 + l;
  float s1 = 0.0f, s2 = 0.0f;
  for (int k = 0; k < 64; ++k) {
    float v = hp[(part * 64 + k) * 1024];
    s1 += v; s2 += v * v;
  }
  p1[part][lq] = s1; p2[part][lq] = s2;
  __syncthreads();
  if (part == 0) {
    float a1 = (p1[0][lq] + p1[1][lq] + p1[2][lq] + p1[3][lq]) * (1.0f / 256.0f);
    float a2 = (p2[0][lq] + p2[1][lq] + p2[2][lq] + p2[3][lq]) * (1.0f / 256.0f);
    float var = a2 - a1 * a1;
    p1[0][lq] = a1;
    p2[0][lq] = 1.0f / sqrtf(var + 1e-5f);
  }
  __syncthreads();
  float mean = p1[0][lq], inv = p2[0][lq];
  float* zp = z + (size_t)b * 262144 + l;
  for (int k = 0; k < 64; ++k) {
    int hh = part * 64 + k;
    float v = hp[hh * 1024];
    zp[hh * 1024] = (v - mean) * inv * g[hh] + bn[hh];
  }
}

// ================= K5: dt/A twiddle tables + Ck =================
__global__ void k_tab(const float* __restrict__ log_dt, const float* __restrict__ Ar,
                      const float* __restrict__ Ai, const float* __restrict__ Cre,
                      const float* __restrict__ Cim,
                      float2* __restrict__ W32, float2* __restrict__ W1, float2* __restrict__ Ck) {
  int gid = blockIdx.x * 256 + threadIdx.x;   // 32768 = H*N
  int h = gid >> 7;
  float dt = expf(log_dt[h]);
  float ar = -expf(Ar[gid]);
  float ai = Ai[gid];
  float dre = dt * ar, dim = dt * ai;
  size_t tb = (size_t)gid * 32;
  for (int j = 0; j < 32; ++j) {
    float sn, cs;
    float e = expf(dre * (float)j);
    sincosf(dim * (float)j, &sn, &cs);
    W1[tb + j] = make_float2(e * cs, e * sn);
    float aj = 32.0f * (float)j;
    float e2 = expf(dre * aj);
    sincosf(dim * aj, &sn, &cs);
    W32[tb + j] = make_float2(e2 * cs, e2 * sn);
  }
  float sn, cs;
  float er = expf(dre);
  sincosf(dim, &sn, &cs);
  float exr = er * cs - 1.0f, exi = er * sn;   // exp(dtA)-1
  float den = ar * ar + ai * ai;               // |A|^2
  float qr = (exr * ar + exi * ai) / den;      // (exp(dtA)-1)/A
  float qi = (exi * ar - exr * ai) / den;
  #pragma unroll
  for (int c = 0; c < 2; ++c) {
    float cr = Cre[c * 32768 + gid], ci = Cim[c * 32768 + gid];
    Ck[c * 32768 + gid] = make_float2(cr * qr - ci * qi, cr * qi + ci * qr);
  }
}

// ================= K6: combined conv kernel Kc =================
__global__ void k_kc(const float2* __restrict__ W32, const float2* __restrict__ W1,
                     const float2* __restrict__ Ck, float* __restrict__ Kc) {
  int j2 = blockIdx.x * 256 + threadIdx.x;  // 0..2047
  int h = blockIdx.y;
  int c, l;
  if (j2 >= 1024) { c = 0; l = j2 - 1024; } else { c = 1; l = 1023 - j2; }
  int l1 = l >> 5, l0 = l & 31;
  const float2* wa = W32 + (size_t)h * 4096;
  const float2* wb = W1 + (size_t)h * 4096;
  const float2* ck = Ck + c * 32768 + h * 128;
  float acc = 0.0f;
  for (int n = 0; n < 128; ++n) {
    float2 a = wa[n * 32 + l1];
    float2 bq = wb[n * 32 + l0];
    float2 k = ck[n];
    float wr = a.x * bq.x - a.y * bq.y;
    float wi = a.x * bq.y + a.y * bq.x;
    acc += k.x * wr - k.y * wi;
  }
  Kc[h * 2048 + j2] = 2.0f * acc;
}

// ================= K7: direct conv + Dp*z + gelu (in place over z) =================
// ks stored pad-swizzled: p(i) = i + 4*(i>>5)  (4 pad words per 32) -> 16B-aligned
// float4 slots; every 8 consecutive lanes cover all 32 banks exactly once => conflict-free.
__global__ __launch_bounds__(128) void k_conv(float* __restrict__ z, const float* __restrict__ Kc,
                                              const float* __restrict__ Dp) {
  __shared__ __align__(16) float zs[1024];
  __shared__ __align__(16) float ks[2304];   // 2048 + 4*64 pad
  int tid = threadIdx.x;
  size_t row = (size_t)blockIdx.x * 1024;
  int h = blockIdx.x & 255;
  #pragma unroll
  for (int q = 0; q < 2; ++q)
    *(float4*)&zs[tid * 8 + q * 4] = *(const float4*)&z[row + tid * 8 + q * 4];
  #pragma unroll
  for (int q = 0; q < 4; ++q) {
    int i = tid * 16 + q * 4;                      // mult of 4, within one 32-block
    float4 v = *(const float4*)&Kc[h * 2048 + i];
    *(float4*)&ks[i + 4 * (i >> 5)] = v;           // padded store, stays 16B-aligned
  }
  __syncthreads();
  int l0 = tid * 8;
  float acc[8] = {};
  for (int mc = 0; mc < 256; ++mc) {
    int m0 = mc * 4;
    const float4 zv = *(const float4*)&zs[m0];
    int b0 = l0 - m0 + 1020;
    int b1 = b0 + 4;
    int b2 = b0 + 8;
    const float4 w0 = *(const float4*)&ks[b0 + 4 * (b0 >> 5)];
    const float4 w1 = *(const float4*)&ks[b1 + 4 * (b1 >> 5)];
    const float4 w2 = *(const float4*)&ks[b2 + 4 * (b2 >> 5)];
    float wf[12] = {w0.x, w0.y, w0.z, w0.w, w1.x, w1.y, w1.z, w1.w, w2.x, w2.y, w2.z, w2.w};
    float zr[4] = {zv.x, zv.y, zv.z, zv.w};
    #pragma unroll
    for (int r = 0; r < 4; ++r) {
      #pragma unroll
      for (int s = 0; s < 8; ++s) acc[s] += zr[r] * wf[s + 4 - r];
    }
  }
  float dp = Dp[h];
  #pragma unroll
  for (int s = 0; s < 8; ++s) {
    float u = acc[s] + dp * zs[l0 + s];
    acc[s] = 0.5f * u * (1.0f + tanhf(0.7978845608028654f * (u + 0.044715f * u * u * u)));
  }
  *(float4*)&z[row + l0]     = make_float4(acc[0], acc[1], acc[2], acc[3]);
  *(float4*)&z[row + l0 + 4] = make_float4(acc[4], acc[5], acc[6], acc[7]);
}

// ================= K10: c1 = relu(conv3_channels(out1)) =================
__global__ __launch_bounds__(128) void k_c1(const float* __restrict__ x1, const float* __restrict__ w,
                                            const float* __restrict__ bb, float* __restrict__ c1) {
  __shared__ float wl[2304];
  int tid = threadIdx.x;
  int b = blockIdx.y, l = blockIdx.x * 128 + tid;
  for (int i = tid; i < 2304; i += 128) wl[i] = w[i];
  __syncthreads();
  const float* xp = x1 + (size_t)b * 262144;
  float a0 = 0.0f, a1 = 0.0f, a2 = 0.0f;
  for (int i = 0; i < 256; ++i) {
    const float* r = xp + i * 1024;
    float v0 = (l >= 1)    ? r[l - 1] : 0.0f;
    float v1 = r[l];
    float v2 = (l <= 1022) ? r[l + 1] : 0.0f;
    const float* w0 = &wl[i * 3];
    a0 += v0 * w0[0]    + v1 * w0[1]    + v2 * w0[2];
    a1 += v0 * w0[768]  + v1 * w0[769]  + v2 * w0[770];
    a2 += v0 * w0[1536] + v1 * w0[1537] + v2 * w0[1538];
  }
  c1[((size_t)b * 3 + 0) * 1024 + l] = fmaxf(a0 + bb[0], 0.0f);
  c1[((size_t)b * 3 + 1) * 1024 + l] = fmaxf(a1 + bb[1], 0.0f);
  c1[((size_t)b * 3 + 2) * 1024 + l] = fmaxf(a2 + bb[2], 0.0f);
}

// ================= K11a: transpose+convert tr2_W (o,i,k)->(i,k,o) =================
__global__ void k_wt(const void* __restrict__ w, float* __restrict__ wt,
                     const int* __restrict__ flag) {
  int gid = blockIdx.x * 256 + threadIdx.x;   // 1572864
  int o = gid & 511, ik = gid >> 9;
  float v;
  if (*flag) v = bf2f(((const unsigned short*)w)[o * 3072 + ik]);
  else       v = ((const float*)w)[o * 3072 + ik];
  wt[gid] = v;
}

// ================= K11: c2 = conv3 over swapped axes =================
__global__ __launch_bounds__(128) void k_c2(const float* __restrict__ c1, const float* __restrict__ wt,
                                            const float* __restrict__ bb, float* __restrict__ c2) {
  __shared__ float c1s[3072];
  int tid = threadIdx.x;
  int b = blockIdx.y, o = blockIdx.x * 128 + tid;
  for (int i = tid; i < 3072; i += 128) c1s[i] = c1[(size_t)b * 3072 + i];
  __syncthreads();
  float a0 = 0.0f, a1 = 0.0f, a2 = 0.0f;
  for (int i = 0; i < 1024; ++i) {
    float w0 = wt[(i * 3 + 0) * 512 + o];
    float w1 = wt[(i * 3 + 1) * 512 + o];
    float w2 = wt[(i * 3 + 2) * 512 + o];
    float x0 = c1s[i], x1 = c1s[1024 + i], x2 = c1s[2048 + i];
    a0 += w1 * x0 + w2 * x1;
    a1 += w0 * x0 + w1 * x1 + w2 * x2;
    a2 += w0 * x1 + w1 * x2;
  }
  float bv = bb[o];
  c2[((size_t)b * 512 + o) * 3 + 0] = a0 + bv;
  c2[((size_t)b * 512 + o) * 3 + 1] = a1 + bv;
  c2[((size_t)b * 512 + o) * 3 + 2] = a2 + bv;
}

// ================= K12: trend = swap(c2 @ poly)  (f32 out) =================
__global__ void k_trend(const float* __restrict__ c2, float* __restrict__ tr) {
  int gid = blockIdx.x * 256 + threadIdx.x;   // 4194304
  int node = gid & 511, h = (gid >> 9) & 255, b = gid >> 17;
  float lin = (float)(h + 1) * (1.0f / 257.0f);
  const float* cp = &c2[((size_t)b * 512 + node) * 3];
  float l2 = lin * lin;
  tr[gid] = cp[0] * lin + cp[1] * l2 + cp[2] * l2 * lin;
}

// ================= K13: FFT over channel axis, top-4, season (f32 out) =================
__global__ __launch_bounds__(256) void k_fft(const float* __restrict__ xin,
                                             float* __restrict__ season) {
  __shared__ float2 S[256][17];
  __shared__ float2 W[128];
  __shared__ float ampL[4][16], frL[4][16], phL[4][16];
  int tid = threadIdx.x;
  int b = blockIdx.y, d0 = blockIdx.x * 16;
  const float* xp = xin + (size_t)b * 262144 + d0;
  if (tid < 128) {
    float sn, cs;
    sincosf((2.0f * PI_F / 256.0f) * (float)tid, &sn, &cs);
    W[tid] = make_float2(cs, -sn);
  }
  #pragma unroll
  for (int r = 0; r < 16; ++r) {
    int idx = tid + 256 * r;
    int t = idx >> 4, c = idx & 15;
    int rt = (int)(__brev((unsigned)t) >> 24);
    S[rt][c] = make_float2(xp[t * 1024 + c], 0.0f);
  }
  __syncthreads();
  for (int s = 0; s < 8; ++s) {
    int half = 1 << s;
    #pragma unroll
    for (int r = 0; r < 8; ++r) {
      int item = tid + 256 * r;
      int c = item & 15, p = item >> 4;
      int j = p & (half - 1);
      int i1 = ((p >> s) << (s + 1)) | j;
      int i2 = i1 + half;
      float2 tw = W[j << (7 - s)];
      float2 a = S[i1][c], bb = S[i2][c];
      float2 tv = make_float2(tw.x * bb.x - tw.y * bb.y, tw.x * bb.y + tw.y * bb.x);
      S[i1][c] = make_float2(a.x + tv.x, a.y + tv.y);
      S[i2][c] = make_float2(a.x - tv.x, a.y - tv.y);
    }
    __syncthreads();
  }
  if (tid < 16) {
    int c = tid;
    float bm0 = -1.0f, bm1 = -1.0f, bm2 = -1.0f, bm3 = -1.0f;
    int k0 = 1, k1 = 1, k2 = 1, k3 = 1;
    for (int k = 1; k <= 127; ++k) {
      float2 v = S[k][c];
      float m2 = v.x * v.x + v.y * v.y;
      if (m2 > bm0)      { bm3 = bm2; k3 = k2; bm2 = bm1; k2 = k1; bm1 = bm0; k1 = k0; bm0 = m2; k0 = k; }
      else if (m2 > bm1) { bm3 = bm2; k3 = k2; bm2 = bm1; k2 = k1; bm1 = m2; k1 = k; }
      else if (m2 > bm2) { bm3 = bm2; k3 = k2; bm2 = m2; k2 = k; }
      else if (m2 > bm3) { bm3 = m2; k3 = k; }
    }
    int ks4[4] = {k0, k1, k2, k3};
    #pragma unroll
    for (int s = 0; s < 4; ++s) {
      int k = ks4[s];
      float2 v = S[k][c];
      ampL[s][c] = 2.0f * sqrtf(v.x * v.x + v.y * v.y);
      phL[s][c] = atan2f(v.y, v.x);
      frL[s][c] = (2.0f * PI_F / 256.0f) * (float)k;
    }
  }
  __syncthreads();
  #pragma unroll
  for (int r = 0; r < 16; ++r) {
    int idx = tid + 256 * r;
    int t = idx >> 4, c = idx & 15;
    float acc = 0.0f;
    #pragma unroll
    for (int s = 0; s < 4; ++s) acc += ampL[s][c] * cosf(frL[s][c] * (float)t + phL[s][c]);
    season[(size_t)b * 262144 + t * 1024 + d0 + c] = acc;
  }
}

// ================= launch =================
extern "C" void kernel_launch(void* const* d_in, const int* in_sizes, int n_in,
                              void* d_out, int out_size, void* d_ws, size_t ws_size,
                              hipStream_t stream) {
  const void* x       = d_in[0];
  const int*  t       = (const int*)d_in[1];
  const void* x_enc   = d_in[2];
  (void)in_sizes; (void)n_in; (void)out_size; (void)ws_size;

  float* out = (float*)d_out;    // f32 outputs (reference output dtype)
  float* ws  = (float*)d_ws;
  float* sf   = ws + OFF_SF;
  float* emb  = ws + OFF_EMB;
  float* m    = ws + OFF_M;
  float2* Ck  = (float2*)(ws + OFF_CK);
  float* Kc   = ws + OFF_KC;
  float* c1   = ws + OFF_C1;
  float* c2   = ws + OFF_C2;
  float* wt   = ws + OFF_WT;
  float2* W32 = (float2*)(ws + OFF_W32);
  float2* W1  = (float2*)(ws + OFF_W1);
  float* xmod = ws + OFF_XMOD;
  float* hbuf = ws + OFF_H;
  float* zbuf = ws + OFF_Z;
  int*   flagp = (int*)(ws + OFF_FLAG);

  // 0. detect input dtype (bf16 vs f32), then convert weights/vectors to f32
  k_detect<<<1, 64, 0, stream>>>(x, flagp);
  #define CVT(idx, off, n) k_cvt<<<((n) + 255) / 256, 256, 0, stream>>>(d_in[idx], ws + (off), (n), flagp)
  CVT(3,  OFF_ADAW,   2097152);   // ada_W
  CVT(4,  OFF_ADAB,   2048);      // ada_b
  CVT(5,  OFF_TRANSW, 65536);     // trans_W
  CVT(6,  OFF_TRANSB, 256);       // trans_b
  CVT(7,  OFF_NORMG,  256);       // norm_g
  CVT(8,  OFF_NORMB,  256);       // norm_b
  CVT(9,  OFF_LOGDT,  256);       // log_dt
  CVT(10, OFF_AR,     32768);     // A_real
  CVT(11, OFF_AI,     32768);     // A_imag
  CVT(12, OFF_CRE,    65536);     // C_re
  CVT(13, OFF_CIM,    65536);     // C_im
  CVT(14, OFF_DP,     256);       // Dp
  CVT(15, OFF_OUTW,   65536);     // out_W
  CVT(16, OFF_OUTB,   256);       // out_b
  CVT(17, OFF_PROJW,  131072);    // proj_W
  CVT(18, OFF_PROJB,  512);       // proj_b
  CVT(19, OFF_TR1W,   2304);      // tr1_W
  CVT(20, OFF_TR1B,   3);         // tr1_b
  CVT(22, OFF_TR2B,   512);       // tr2_b
  CVT(23, OFF_LINW,   524288);    // lin_W
  CVT(24, OFF_LINB,   512);       // lin_b
  #undef CVT

  // 1. time embedding -> modulation params
  k_sf<<<128, 256, 0, stream>>>(t, sf);
  k_emb<<<dim3(2048, 32), 64, 0, stream>>>(sf, ws + OFF_ADAW, ws + OFF_ADAB, emb);
  // 2. LN(L) + modulate
  k_ln_mod<<<8192, 256, 0, stream>>>(x, emb, xmod, flagp);
  // outputs 0/1 early
  k_meanH<<<512, 256, 0, stream>>>(xmod, m);
  k_sub<<<8192, 256, 0, stream>>>(xmod, m, out + OOUT0);
  k_lin<<<dim3(512, 32), 64, 0, stream>>>(m, ws + OFF_LINW, ws + OFF_LINB, out + OOUT1);
  // 3. h = xmod + trans_W @ x_enc + trans_b
  k_mm<0><<<dim3(16, 4, 32), 256, 0, stream>>>(ws + OFF_TRANSW, x_enc, ws + OFF_TRANSB, xmod, hbuf, 0, flagp);
  // 4. z = LN_H(h) * g + b
  k_lnH<<<512, 256, 0, stream>>>(hbuf, ws + OFF_NORMG, ws + OFF_NORMB, zbuf);
  // 5. S4 kernel
  k_tab<<<128, 256, 0, stream>>>(ws + OFF_LOGDT, ws + OFF_AR, ws + OFF_AI, ws + OFF_CRE, ws + OFF_CIM, W32, W1, Ck);
  k_kc<<<dim3(8, 256), 256, 0, stream>>>(W32, W1, Ck, Kc);
  // 6. y = conv(z,Kc); gelu(y + Dp*z) in place
  k_conv<<<8192, 128, 0, stream>>>(zbuf, Kc, ws + OFF_DP);
  // 7. out = swish(out_W @ ygelu + out_b + h)
  k_mm<1><<<dim3(16, 4, 32), 256, 0, stream>>>(ws + OFF_OUTW, zbuf, ws + OFF_OUTB, hbuf, xmod, 0, flagp);
  // 8. p = proj_W @ out + proj_b; halves -> zbuf (out1) / hbuf (out2)
  k_mm<2><<<dim3(16, 4, 32), 256, 0, stream>>>(ws + OFF_PROJW, xmod, ws + OFF_PROJB, ws, zbuf, 0, flagp);
  k_mm<2><<<dim3(16, 4, 32), 256, 0, stream>>>(ws + OFF_PROJW, xmod, ws + OFF_PROJB, ws, hbuf, 256, flagp);
  // 9. trend path
  k_c1<<<dim3(8, 32), 128, 0, stream>>>(zbuf, ws + OFF_TR1W, ws + OFF_TR1B, c1);
  k_wt<<<6144, 256, 0, stream>>>(d_in[21], wt, flagp);
  k_c2<<<dim3(4, 32), 128, 0, stream>>>(c1, wt, ws + OFF_TR2B, c2);
  k_trend<<<16384, 256, 0, stream>>>(c2, out + OTREND);
  // 10. season path
  k_fft<<<dim3(64, 32), 256, 0, stream>>>(hbuf, out + OSEASON);
}